// Round 7
// baseline (504.770 us; speedup 1.0000x reference)
//
#include <hip/hip_runtime.h>
#include <hip/hip_bf16.h>
#include <math.h>

#define NN 8192
#define FF 64
#define HH 128
#define RR 3
#define DEG 32
#define KK 32
#define EE (NN*DEG)
#define DD 131            // 2F+3
#define TEMP 0.3f
#define NEG_SLOPE 0.2f
#define EPS_LN 1e-5f
#define W_THRESH 1e-6f

typedef float v2f __attribute__((ext_vector_type(2)));
__device__ __forceinline__ float4 ld4(const float* p) { return *(const float4*)p; }
#define PKFMA(a, b, c) __builtin_elementwise_fma((a), (b), (c))
#define GIDX(r, g) gaccv[r][(g)>>1][(g)&1]

// ws layout (floats):
//  [0..127]   hdr: [0]=contagion_sum [1..3]=regime_probs [4]=amp [8..71]=colsum
//  [128 .. 128+EE)  edge scores
//  [tabs ..)  PA1, PA2 prefix tables
//
// INVARIANT (R15): per-edge score arithmetic must replicate the reference's
// ascending-k FMA chain BITWISE; LN/Ws2 lane mapping + reduction order is
// proven-passing and must not change.
// R17 (banked): LDS-staged W panels + T14 async prefetch -> 308.6us edge.
// R18 (failed): W direct-from-L2 exposes latency. R20 (null): unroll pragma,
// compiler already unrolled.
// R21 MODEL REVISION: the edge kernel is LDS-DELIVERY-bound, not VALU-bound:
// 18.9GB LDS reads / 69TB/s = 273us of the 309us. Dual-GEMM per-k: 10 LDS
// reads vs 32 pk_fma (108 vs 64 cyc).
// R21 (this round): reshard dual-GEMM 2edge x 16col -> 4edge x 8col with
// transposed EIB_T[k][edge]: per-k = 1 broadcast a-read + 4 w-reads (~60 cyc)
// — balanced with VALU. h chains bit-identical (same per-col ascending-k FMA,
// same v2f pairing; only the owning lane changes). LN keeps its exact old
// mapping/order via an hS[64][132] LDS round-trip. ehTh gets identical values
// in identical layout (write order bank-swizzled by cd: row-step 8*68 ≡ 0
// mod 32 banks). Gating/Gbuf/finalize untouched.
// NOTE (R7/R8): no second __launch_bounds__ arg — collapses VGPR, spills.
// NOTE (R10): v_pk_fma_f32 — each component is an exact IEEE FMA.
// NOTE (R11): 512-thr/128-edge blocks regress; 256-thr/64-edge is the sweet spot.
// NOTE (R12/R19): standalone finalize; non-edge residual has ±20us run noise.
// NOTE (R14): keep regime as a standalone dispatch.

// ---------------- Setup kernel: blocks 0..1023 = prefix tables (col-halved), 1024..1151 = stats ----------------
__global__ __launch_bounds__(256) void setup_kernel(
    const float* __restrict__ x,
    const float* __restrict__ Ws1, const float* __restrict__ Wp,
    const float* __restrict__ Wc1, const float* __restrict__ bc1,
    const float* __restrict__ Wc2, const float* __restrict__ bc2,
    float* __restrict__ PA, float* __restrict__ hdr)
{
    __shared__ float spool[12608];
    int t = threadIdx.x;
    int bid = blockIdx.x;

    if (bid < 1024) {
        float* xs = spool;          // [32][65]
        float* wl = spool + 2080;   // [64][64]
        int which = bid & 1;
        int ch    = (bid >> 1) & 1;   // column half
        int n0    = (bid >> 2) * 32;
        const float* base = which ? Wp : Ws1;

        for (int i = t; i < 2048; i += 256)
            xs[(i >> 6) * 65 + (i & 63)] = x[n0 * 64 + i];
        for (int it = 0; it < 4; it++) {
            int flat = (t + it * 256) * 4;     // 0..4092
            int r = flat >> 6, c = flat & 63;
            *(float4*)&wl[flat] = ld4(&base[r * 128 + ch * 64 + c]);
        }
        __syncthreads();

        int row = t >> 3, colg = t & 7;        // 32 rows x 8 col-groups
        float acc[8];
        #pragma unroll
        for (int j = 0; j < 8; j++) acc[j] = 0.f;
        const float* xr = &xs[row * 65];
        for (int k = 0; k < 64; k++) {
            float a = xr[k];
            const float* wr = &wl[k * 64 + colg * 8];
            #pragma unroll
            for (int jj = 0; jj < 2; jj++) {
                float4 w = ld4(wr + 4 * jj);
                acc[4*jj+0] += a * w.x; acc[4*jj+1] += a * w.y;
                acc[4*jj+2] += a * w.z; acc[4*jj+3] += a * w.w;
            }
        }
        float* outp = PA + (size_t)which * (NN * 128) + (size_t)(n0 + row) * 128 + ch * 64 + colg * 8;
        #pragma unroll
        for (int j = 0; j < 8; j++) outp[j] = acc[j];
    } else {
        float* xs = spool;          // [64][65]
        float* wl = spool + 4160;   // [64][128]
        float* cs = spool + 12352;  // [4][64]
        int n0 = (bid - 1024) * 64;

        for (int i = 0; i < 16; i++) {
            int flat = t + i * 256;
            int r = flat >> 6, c = flat & 63;
            xs[r * 65 + c] = x[(n0 + r) * 64 + c];
        }
        for (int i = 0; i < 8; i++) {
            int flat = (t + i * 256) * 4;
            *(float4*)&wl[flat] = ld4(&Wc1[flat]);
        }
        __syncthreads();

        {
            int col = t & 63, g = t >> 6;
            float ps = 0.f;
            for (int r = g * 16; r < g * 16 + 16; r++) ps += xs[r * 65 + col];
            cs[g * 64 + col] = ps;
        }
        __syncthreads();
        if (t < 64) {
            float v = cs[t] + cs[64 + t] + cs[128 + t] + cs[192 + t];
            atomicAdd(&hdr[8 + t], v);
        }

        int r = t >> 2, q = t & 3;
        float accl = 0.f;
        for (int hh = 0; hh < 32; hh++) {
            int h = hh * 4 + q;
            float s = bc1[h];
            for (int i = 0; i < 64; i++) s += xs[r * 65 + i] * wl[i * 128 + h];
            accl += fmaxf(s, 0.f) * Wc2[h];
        }
        accl += __shfl_xor(accl, 1);
        accl += __shfl_xor(accl, 2);
        if (q == 0) {
            float lvl = 1.f / (1.f + expf(-(accl + bc2[0])));
            atomicAdd(&hdr[0], lvl);
        }
    }
}

// ---------------- Kernel B: regime probs + amp ----------------
__global__ __launch_bounds__(128) void regime_kernel(
    const float* __restrict__ Wr1, const float* __restrict__ br1,
    const float* __restrict__ Wr2, const float* __restrict__ br2,
    float* __restrict__ hdr)
{
    __shared__ float gsl[64];
    __shared__ float t1[128];
    int t = threadIdx.x;
    if (t < 64) gsl[t] = hdr[8 + t] * (1.f / (float)NN);
    __syncthreads();
    float a = br1[t];
    for (int i = 0; i < 64; i++) a += gsl[i] * Wr1[i * 128 + t];
    t1[t] = fmaxf(a, 0.f);
    __syncthreads();
    if (t < 3) {
        float v = br2[t];
        for (int h = 0; h < 128; h++) v += t1[h] * Wr2[h * 3 + t];
        gsl[32 + t] = v;
    }
    __syncthreads();
    if (t == 0) {
        float v0 = gsl[32], v1 = gsl[33], v2 = gsl[34];
        float m = fmaxf(v0, fmaxf(v1, v2));
        float e0 = expf(v0 - m), e1 = expf(v1 - m), e2 = expf(v2 - m);
        float inv = 1.f / (e0 + e1 + e2);
        hdr[1] = e0 * inv; hdr[2] = e1 * inv; hdr[3] = e2 * inv;
        hdr[4] = 1.f + 0.5f * (hdr[0] * (1.f / (float)NN));
    }
}

// ---------------- Fused edge kernel: R21 resharded dual-GEMM ----------------
// LDS pool (floats), 8512 fl = 34048 B:
//   phase A: WPan[2][12][128] @0 (3072), EIB_T[72][68] @3072 (4896) -> 7968
//   redistribution: hS[64][132] @0 (8448)   (aliases WPan+EIB_T, both dead)
//   phase B: ehTh[64][68] @0 (4352), WgPan[3][16][64] @4352 (3072)
//   phase C: Gbuf[64][68] @0
//   persistent: rawS @8448 (64)
#define EIBT_S 68
#define HS_S 132
__global__ __launch_bounds__(256) void edge_fused_kernel(
    const int* __restrict__ tgt_idx, const float* __restrict__ edge_attr,
    const float* __restrict__ x,
    const float* __restrict__ Ws1, const float* __restrict__ bs1,
    const float* __restrict__ ln_g, const float* __restrict__ ln_b,
    const float* __restrict__ Ws2, const float* __restrict__ bs2,
    const float* __restrict__ Wp, const float* __restrict__ bp,
    const float* __restrict__ Wg1, const float* __restrict__ bg1,
    const float* __restrict__ Wg2, const float* __restrict__ bg2,
    const float* __restrict__ PA1, const float* __restrict__ PA2,
    const float* __restrict__ hdr, float* __restrict__ scores)
{
    __shared__ float pool[8512];
    float* WPan  = pool;            // [2][12][128]
    float* EIB_T = pool + 3072;     // [72][68]: row k -> 64 edges (+pad)
    float* hS    = pool;            // [64][132]
    float* ehTh  = pool;            // [64][68]
    float* WgPan = pool + 4352;     // [3][16][64]
    float* Gbuf  = pool;            // [64][68]
    float* rawS  = pool + 8448;     // [64]

    int t = threadIdx.x;
    int e0 = blockIdx.x * 64;

    // ---- stage transposed edge input: EIB_T[k][edge]; rows 64..66 attr, 67..71 zero ----
    {
        int r = t >> 2, q = t & 3;
        int ge = e0 + r;
        int tg = tgt_idx[ge];
        #pragma unroll
        for (int i = 0; i < 4; i++) {
            int col = q * 16 + 4 * i;
            float4 v = ld4(&x[tg * 64 + col]);
            EIB_T[(col + 0) * EIBT_S + r] = v.x;
            EIB_T[(col + 1) * EIBT_S + r] = v.y;
            EIB_T[(col + 2) * EIBT_S + r] = v.z;
            EIB_T[(col + 3) * EIBT_S + r] = v.w;
        }
        if (q == 0) {
            EIB_T[64 * EIBT_S + r] = edge_attr[(size_t)ge * 3 + 0];
            EIB_T[65 * EIBT_S + r] = edge_attr[(size_t)ge * 3 + 1];
            EIB_T[66 * EIBT_S + r] = edge_attr[(size_t)ge * 3 + 2];
        }
    }
    if (t < 320) EIB_T[(67 + (t >> 6)) * EIBT_S + (t & 63)] = 0.f;

    // ---- per-thread staging descriptors (unchanged from R17) ----
    int spr0, spc0, sdst0, spr1, spc1, sdst1, spr2, spc2, sdst2;
    const float *ssrc0, *ssrc1, *ssrc2;
    {
        int fid, mat, loc;
        fid = t;            mat = (fid >= 384) ? 1 : 0; loc = fid - mat * 384;
        spr0 = loc >> 5; spc0 = (loc & 31) * 4; sdst0 = mat * 1536 + spr0 * 128 + spc0;
        ssrc0 = mat ? Wp : Ws1;
        fid = 256 + t;      mat = (fid >= 384) ? 1 : 0; loc = fid - mat * 384;
        spr1 = loc >> 5; spc1 = (loc & 31) * 4; sdst1 = mat * 1536 + spr1 * 128 + spc1;
        ssrc1 = mat ? Wp : Ws1;
        fid = 512 + t;      mat = (fid >= 384) ? 1 : 0; loc = fid - mat * 384;
        spr2 = loc >> 5; spc2 = (loc & 31) * 4; sdst2 = mat * 1536 + spr2 * 128 + spc2;
        ssrc2 = mat ? Wp : Ws1;
    }
    int gdst0, gdst1, gdst2, goff0, goff1, goff2;
    {
        int fid, rr, loc, pr, pc;
        fid = t;        rr = fid >> 8; loc = fid & 255; pr = loc >> 4; pc = (loc & 15) * 4;
        gdst0 = rr * 1024 + pr * 64 + pc; goff0 = rr * 8192 + pr * 64 + pc;
        fid = 256 + t;  rr = fid >> 8; loc = fid & 255; pr = loc >> 4; pc = (loc & 15) * 4;
        gdst1 = rr * 1024 + pr * 64 + pc; goff1 = rr * 8192 + pr * 64 + pc;
        fid = 512 + t;  rr = fid >> 8; loc = fid & 255; pr = loc >> 4; pc = (loc & 15) * 4;
        gdst2 = rr * 1024 + pr * 64 + pc; goff2 = rr * 8192 + pr * 64 + pc;
    }

    #define LOADP(pp, w0_, w1_, w2_)                                          \
      { int _pr0 = 64 + (pp) * 12 + spr0;                                     \
        int _pr1 = 64 + (pp) * 12 + spr1;                                     \
        int _pr2 = 64 + (pp) * 12 + spr2;                                     \
        w0_ = (_pr0 < 131) ? ld4(&ssrc0[_pr0 * 128 + spc0]) : make_float4(0.f,0.f,0.f,0.f); \
        w1_ = (_pr1 < 131) ? ld4(&ssrc1[_pr1 * 128 + spc1]) : make_float4(0.f,0.f,0.f,0.f); \
        w2_ = (_pr2 < 131) ? ld4(&ssrc2[_pr2 * 128 + spc2]) : make_float4(0.f,0.f,0.f,0.f); }

    #define LOADG(gi_, g0_, g1_, g2_)                                         \
      { g0_ = ld4(&Wg1[goff0 + (gi_) * 1024]);                                \
        g1_ = ld4(&Wg1[goff1 + (gi_) * 1024]);                                \
        g2_ = ld4(&Wg1[goff2 + (gi_) * 1024]); }

    // ---- new GEMM sharding: 4 edges x 8 cols per thread ----
    int ed = t >> 4, cd = t & 15;
    int eb = ed * 4, cb = cd * 8;
    int srcg = (e0 + eb) >> 5;

    v2f aS[4][4], aP[4][4];   // [edge][col-pair]; cols cb..cb+7
    {
        const float* p1 = &PA1[(size_t)srcg * 128 + cb];
        const float* p2 = &PA2[(size_t)srcg * 128 + cb];
        float4 v0 = ld4(p1), v1 = ld4(p1 + 4);
        float4 u0 = ld4(p2), u1 = ld4(p2 + 4);
        #pragma unroll
        for (int e = 0; e < 4; e++) {
            aS[e][0] = (v2f){ v0.x, v0.y }; aS[e][1] = (v2f){ v0.z, v0.w };
            aS[e][2] = (v2f){ v1.x, v1.y }; aS[e][3] = (v2f){ v1.z, v1.w };
            aP[e][0] = (v2f){ u0.x, u0.y }; aP[e][1] = (v2f){ u0.z, u0.w };
            aP[e][2] = (v2f){ u1.x, u1.y }; aP[e][3] = (v2f){ u1.z, u1.w };
        }
    }

    // ---- fused dual-GEMM k-loop: 6 panels x 12 rows (original k = 64..135) ----
    float4 wra, wrb, wrc;
    LOADP(0, wra, wrb, wrc);
    for (int p = 0; p < 6; p++) {
        __syncthreads();                       // prior panel reads done
        *(float4*)&WPan[sdst0] = wra;
        *(float4*)&WPan[sdst1] = wrb;
        *(float4*)&WPan[sdst2] = wrc;
        if (p < 5) LOADP(p + 1, wra, wrb, wrc);
        __syncthreads();                       // WPan (and EIB_T at p=0) visible
        #pragma unroll
        for (int kk = 0; kk < 12; kk++) {
            int k = p * 12 + kk;
            float4 av = ld4(&EIB_T[k * EIBT_S + eb]);     // 4 edges, wave-broadcast
            const float* ws = &WPan[kk * 128 + cb];
            const float* wq = ws + 1536;
            float4 w1 = ld4(ws), w2 = ld4(ws + 4);
            float4 q1 = ld4(wq), q2 = ld4(wq + 4);
            v2f w1a = { w1.x, w1.y }, w1b = { w1.z, w1.w };
            v2f w1c = { w2.x, w2.y }, w1d = { w2.z, w2.w };
            v2f q1a = { q1.x, q1.y }, q1b = { q1.z, q1.w };
            v2f q1c = { q2.x, q2.y }, q1d = { q2.z, q2.w };
            float ae[4] = { av.x, av.y, av.z, av.w };
            #pragma unroll
            for (int e = 0; e < 4; e++) {
                v2f aa = { ae[e], ae[e] };
                aS[e][0] = PKFMA(aa, w1a, aS[e][0]);
                aS[e][1] = PKFMA(aa, w1b, aS[e][1]);
                aS[e][2] = PKFMA(aa, w1c, aS[e][2]);
                aS[e][3] = PKFMA(aa, w1d, aS[e][3]);
                aP[e][0] = PKFMA(aa, q1a, aP[e][0]);
                aP[e][1] = PKFMA(aa, q1b, aP[e][1]);
                aP[e][2] = PKFMA(aa, q1c, aP[e][2]);
                aP[e][3] = PKFMA(aa, q1d, aP[e][3]);
            }
        }
    }

    // ---- redistribute h (score path) to the old LN lane mapping via hS ----
    __syncthreads();                           // all WPan/EIB_T reads done; hS may alias
    #pragma unroll
    for (int e = 0; e < 4; e++) {
        float4 g0, g1;
        g0.x = aS[e][0][0]; g0.y = aS[e][0][1]; g0.z = aS[e][1][0]; g0.w = aS[e][1][1];
        g1.x = aS[e][2][0]; g1.y = aS[e][2][1]; g1.z = aS[e][3][0]; g1.w = aS[e][3][1];
        *(float4*)&hS[(eb + e) * HS_S + cb]     = g0;
        *(float4*)&hS[(eb + e) * HS_S + cb + 4] = g1;
    }
    float4 gra, grb, grc;
    LOADG(0, gra, grb, grc);                   // prefetch lands under LN phase
    __syncthreads();                           // hS visible

    // ---- +bias, LayerNorm, LeakyReLU, dot Ws2 (verbatim old mapping & order) ----
    int tcol = t & 7, trow = t >> 3;
    {
        float h0[16], h1[16];
        #pragma unroll
        for (int jj = 0; jj < 4; jj++) {
            float4 a0 = ld4(&hS[(2 * trow) * HS_S + tcol * 4 + jj * 32]);
            float4 a1 = ld4(&hS[(2 * trow + 1) * HS_S + tcol * 4 + jj * 32]);
            h0[jj*4+0] = a0.x; h0[jj*4+1] = a0.y; h0[jj*4+2] = a0.z; h0[jj*4+3] = a0.w;
            h1[jj*4+0] = a1.x; h1[jj*4+1] = a1.y; h1[jj*4+2] = a1.z; h1[jj*4+3] = a1.w;
        }
        float s0 = 0.f, ss0 = 0.f, s1 = 0.f, ss1 = 0.f;
        #pragma unroll
        for (int j = 0; j < 16; j++) {
            int col = tcol * 4 + (j >> 2) * 32 + (j & 3);
            float b = bs1[col];
            float u0 = h0[j] + b;  h0[j] = u0;
            float u1 = h1[j] + b;  h1[j] = u1;
            s0 += u0; ss0 += u0 * u0;
            s1 += u1; ss1 += u1 * u1;
        }
        #pragma unroll
        for (int m = 1; m < 8; m <<= 1) {
            s0 += __shfl_xor(s0, m);  ss0 += __shfl_xor(ss0, m);
            s1 += __shfl_xor(s1, m);  ss1 += __shfl_xor(ss1, m);
        }
        float mu0 = s0 * (1.f / 128.f), mu1 = s1 * (1.f / 128.f);
        float var0 = ss0 * (1.f / 128.f) - mu0 * mu0;
        float var1 = ss1 * (1.f / 128.f) - mu1 * mu1;
        float inv0 = 1.f / sqrtf(var0 + EPS_LN);
        float inv1 = 1.f / sqrtf(var1 + EPS_LN);
        float d0 = 0.f, d1 = 0.f;
        #pragma unroll
        for (int j = 0; j < 16; j++) {
            int col = tcol * 4 + (j >> 2) * 32 + (j & 3);
            float g = ln_g[col], bb = ln_b[col], w2 = Ws2[col];
            float y0 = (h0[j] - mu0) * inv0 * g + bb;
            float y1 = (h1[j] - mu1) * inv1 * g + bb;
            y0 = (y0 >= 0.f) ? y0 : NEG_SLOPE * y0;
            y1 = (y1 >= 0.f) ? y1 : NEG_SLOPE * y1;
            d0 += y0 * w2; d1 += y1 * w2;
        }
        #pragma unroll
        for (int m = 1; m < 8; m <<= 1) {
            d0 += __shfl_xor(d0, m); d1 += __shfl_xor(d1, m);
        }
        if (tcol == 0) {
            rawS[2 * trow]     = d0 + bs2[0];
            rawS[2 * trow + 1] = d1 + bs2[0];
        }
    }

    // ================= gating: two 64-k halves of ehT (identical values/layout) =================
    int gtr = t >> 4, gtc = t & 15;
    int grow = t >> 2, gq = t & 3;

    v2f gaccv[3][8];
    #pragma unroll
    for (int rr = 0; rr < 3; rr++)
        #pragma unroll
        for (int j = 0; j < 8; j++) gaccv[rr][j] = (v2f){ 0.f, 0.f };

    for (int hf = 0; hf < 2; hf++) {
        __syncthreads();                       // hS reads done (hf=0) / prior ehTh reads done
        if ((cd >> 3) == hf) {                 // this thread's 8 cols live in this half
            int lcb = cb - hf * 64;            // 0..56
            #pragma unroll
            for (int jo = 0; jo < 8; jo++) {
                int j = (jo + cd) & 7;         // bank swizzle: row-step 8*68 ≡ 0 mod 32 banks
                int c = cb + j;
                float b = bp[c];
                float4 g;
                g.x = fmaxf(aP[0][j >> 1][j & 1] + b, 0.f);
                g.y = fmaxf(aP[1][j >> 1][j & 1] + b, 0.f);
                g.z = fmaxf(aP[2][j >> 1][j & 1] + b, 0.f);
                g.w = fmaxf(aP[3][j >> 1][j & 1] + b, 0.f);
                *(float4*)&ehTh[(lcb + j) * 68 + eb] = g;
            }
        }
        for (int p = 0; p < 4; p++) {
            __syncthreads();                   // ehTh writes visible (p==0) / prior panel reads done
            *(float4*)&WgPan[gdst0] = gra;
            *(float4*)&WgPan[gdst1] = grb;
            *(float4*)&WgPan[gdst2] = grc;
            {
                int gi = hf * 4 + p;
                if (gi < 7) LOADG(gi + 1, gra, grb, grc);
            }
            __syncthreads();
            #pragma unroll
            for (int kk = 0; kk < 16; kk++) {
                float4 av = ld4(&ehTh[(p * 16 + kk) * 68 + 4 * gtr]);
                v2f ax = { av.x, av.x }, ay = { av.y, av.y };
                v2f az = { av.z, av.z }, aw = { av.w, av.w };
                #pragma unroll
                for (int rr = 0; rr < 3; rr++) {
                    float4 bv = ld4(&WgPan[rr * 1024 + kk * 64 + 4 * gtc]);
                    v2f bva = { bv.x, bv.y }, bvb = { bv.z, bv.w };
                    gaccv[rr][0] = PKFMA(ax, bva, gaccv[rr][0]);
                    gaccv[rr][1] = PKFMA(ax, bvb, gaccv[rr][1]);
                    gaccv[rr][2] = PKFMA(ay, bva, gaccv[rr][2]);
                    gaccv[rr][3] = PKFMA(ay, bvb, gaccv[rr][3]);
                    gaccv[rr][4] = PKFMA(az, bva, gaccv[rr][4]);
                    gaccv[rr][5] = PKFMA(az, bvb, gaccv[rr][5]);
                    gaccv[rr][6] = PKFMA(aw, bva, gaccv[rr][6]);
                    gaccv[rr][7] = PKFMA(aw, bvb, gaccv[rr][7]);
                }
            }
        }
    }

    // ---- Gbuf + p-phase per regime (unchanged) ----
    float gc = 0.f;
    for (int rr = 0; rr < 3; rr++) {
        __syncthreads();
        #pragma unroll
        for (int j = 0; j < 4; j++) {
            float b = bg1[rr * 64 + 4 * gtc + j];
            float4 g;
            g.x = fmaxf(GIDX(rr, 0  + j) + b, 0.f);
            g.y = fmaxf(GIDX(rr, 4  + j) + b, 0.f);
            g.z = fmaxf(GIDX(rr, 8  + j) + b, 0.f);
            g.w = fmaxf(GIDX(rr, 12 + j) + b, 0.f);
            *(float4*)&Gbuf[(4 * gtc + j) * 68 + 4 * gtr] = g;
        }
        __syncthreads();
        float pacc = 0.f;
        #pragma unroll
        for (int j = 0; j < 16; j++) {
            int m = gq * 4 + (j >> 2) * 16 + (j & 3);
            pacc += Gbuf[m * 68 + grow] * Wg2[rr * 64 + m];
        }
        pacc += __shfl_xor(pacc, 1);
        pacc += __shfl_xor(pacc, 2);
        float gate = 1.f / (1.f + expf(-(pacc + bg2[rr])));
        gc += gate * hdr[1 + rr];
    }
    if (gq == 0) scores[e0 + grow] = rawS[grow] * gc * hdr[4];
}

// ---------------- Kernel D: dedup + softmax + stable top-k, 2 rows per block ----------------
__global__ __launch_bounds__(64) void finalize_kernel(
    const int* __restrict__ tgt_idx, const float* __restrict__ scores,
    float* __restrict__ out_w, float* __restrict__ out_i)
{
    __shared__ int   tl[64];
    __shared__ float pl[64];
    int j = threadIdx.x;
    int half = j >> 5;
    int jl = j & 31;
    int hb = half * 32;
    int row = blockIdx.x * 2 + half;
    int   tg = tgt_idx[row * 32 + jl];
    float s  = scores[row * 32 + jl];
    tl[j] = tg;
    __syncthreads();

    bool alive = true;
    for (int j2 = jl + 1; j2 < 32; j2++)
        if (tl[hb + j2] == tg) { alive = false; break; }
    float z = alive ? s * (1.f / TEMP) : -INFINITY;
    float m = z;
    #pragma unroll
    for (int mm = 1; mm < 32; mm <<= 1) m = fmaxf(m, __shfl_xor(m, mm));
    float p = alive ? expf(z - m) : 0.f;
    float sum = p;
    #pragma unroll
    for (int mm = 1; mm < 32; mm <<= 1) sum += __shfl_xor(sum, mm);
    p = p / sum;
    pl[j] = alive ? p : -1.f;
    __syncthreads();

    int rank = 0, dcount = 0;
    for (int j2 = 0; j2 < 32; j2++) {
        float pj = pl[hb + j2];
        if (pj >= 0.f) {
            dcount++;
            if (alive) {
                if (pj > p || (pj == p && tl[hb + j2] < tg)) rank++;
            }
        }
    }
    if (alive) {
        out_w[row * 32 + rank] = (p > W_THRESH) ? p : 0.f;
        out_i[row * 32 + rank] = (float)tg;
    }
    if (jl == 0) {
        int c = 0;
        for (int slot = dcount; slot < 32; slot++) {
            for (;;) {
                bool found = false;
                for (int q = 0; q < 32; q++) if (tl[hb + q] == c) { found = true; break; }
                if (!found) break;
                c++;
            }
            out_w[row * 32 + slot] = 0.f;
            out_i[row * 32 + slot] = (float)c;
            c++;
        }
    }
}

extern "C" void kernel_launch(void* const* d_in, const int* in_sizes, int n_in,
                              void* d_out, int out_size, void* d_ws, size_t ws_size,
                              hipStream_t stream)
{
    const float* x          = (const float*)d_in[0];
    const int*   edge_index = (const int*)  d_in[1];
    const float* edge_attr  = (const float*)d_in[2];
    const float* Ws1 = (const float*)d_in[3];
    const float* bs1 = (const float*)d_in[4];
    const float* ln_g = (const float*)d_in[5];
    const float* ln_b = (const float*)d_in[6];
    const float* Ws2 = (const float*)d_in[7];
    const float* bs2 = (const float*)d_in[8];
    const float* Wp  = (const float*)d_in[9];
    const float* bp  = (const float*)d_in[10];
    const float* Wr1 = (const float*)d_in[11];
    const float* br1 = (const float*)d_in[12];
    const float* Wr2 = (const float*)d_in[13];
    const float* br2 = (const float*)d_in[14];
    const float* Wg1 = (const float*)d_in[15];
    const float* bg1 = (const float*)d_in[16];
    const float* Wg2 = (const float*)d_in[17];
    const float* bg2 = (const float*)d_in[18];
    const float* Wc1 = (const float*)d_in[19];
    const float* bc1 = (const float*)d_in[20];
    const float* Wc2 = (const float*)d_in[21];
    const float* bc2 = (const float*)d_in[22];

    float* hdr    = (float*)d_ws;
    float* scores = hdr + 128;
    float* tabs   = scores + EE;            // PA1, PA2
    const int* tgt = edge_index + EE;       // row 1 of edge_index

    hipMemsetAsync(d_ws, 0, 512, stream);
    setup_kernel<<<1152, 256, 0, stream>>>(x, Ws1, Wp, Wc1, bc1, Wc2, bc2, tabs, hdr);
    regime_kernel<<<1, 128, 0, stream>>>(Wr1, br1, Wr2, br2, hdr);
    edge_fused_kernel<<<EE / 64, 256, 0, stream>>>(
        tgt, edge_attr, x, Ws1, bs1, ln_g, ln_b, Ws2, bs2, Wp, bp,
        Wg1, bg1, Wg2, bg2, tabs, tabs + (size_t)NN * 128, hdr, scores);
    finalize_kernel<<<NN / 2, 64, 0, stream>>>(
        tgt, scores, (float*)d_out, (float*)d_out + NN * KK);
}